// Round 1
// baseline (293.903 us; speedup 1.0000x reference)
//
#include <hip/hip_runtime.h>

#define D_FEAT 64

// deg[i] = 1.0f  (self-loop contribution to degree)
__global__ void k_init_deg(float* __restrict__ deg, int n) {
    int i = blockIdx.x * blockDim.x + threadIdx.x;
    if (i < n) deg[i] = 1.0f;
}

// deg[col[e]] += 1 over all edges
__global__ void k_count_deg(const int* __restrict__ col, float* __restrict__ deg, int E) {
    int e = blockIdx.x * blockDim.x + threadIdx.x;
    if (e < E) atomicAdd(&deg[col[e]], 1.0f);
}

// deg -> rsqrt(deg) in place (deg >= 1 always, so no zero guard needed)
__global__ void k_deg_to_dis(float* __restrict__ deg, int n) {
    int i = blockIdx.x * blockDim.x + threadIdx.x;
    if (i < n) deg[i] = rsqrtf(deg[i]);
}

// out[i][f] = dis[i]^2 * x[i][f]   (self-loop term; also initializes out)
__global__ void k_self_init(const float* __restrict__ x, const float* __restrict__ dis,
                            float* __restrict__ out, int total) {
    int idx = blockIdx.x * blockDim.x + threadIdx.x;
    if (idx < total) {
        int node = idx >> 6;  // /D_FEAT
        float s = dis[node];
        out[idx] = s * s * x[idx];
    }
}

// one wave (64 lanes) per edge, lane = feature index
__global__ void k_scatter(const int* __restrict__ row, const int* __restrict__ col,
                          const float* __restrict__ x, const float* __restrict__ dis,
                          float* __restrict__ out, int E) {
    int gtid = blockIdx.x * blockDim.x + threadIdx.x;
    int edge = gtid >> 6;
    int lane = threadIdx.x & 63;
    if (edge < E) {
        int r = row[edge];
        int c = col[edge];
        float nrm = dis[r] * dis[c];
        atomicAdd(&out[r * D_FEAT + lane], nrm * x[c * D_FEAT + lane]);
    }
}

extern "C" void kernel_launch(void* const* d_in, const int* in_sizes, int n_in,
                              void* d_out, int out_size, void* d_ws, size_t ws_size,
                              hipStream_t stream) {
    const float* x = (const float*)d_in[0];
    const int* ei = (const int*)d_in[1];

    const int N = in_sizes[0] / D_FEAT;       // 100000
    const int E = in_sizes[1] / 2;            // 1000000
    const int* row = ei;                       // edge_index[0]
    const int* col = ei + E;                   // edge_index[1]

    float* out = (float*)d_out;
    float* deg = (float*)d_ws;                 // N floats of scratch

    const int B = 256;

    k_init_deg<<<(N + B - 1) / B, B, 0, stream>>>(deg, N);
    k_count_deg<<<(E + B - 1) / B, B, 0, stream>>>(col, deg, E);
    k_deg_to_dis<<<(N + B - 1) / B, B, 0, stream>>>(deg, N);

    int total = N * D_FEAT;
    k_self_init<<<(total + B - 1) / B, B, 0, stream>>>(x, deg, out, total);

    // one wave per edge -> E*64 threads
    long long scatter_threads = (long long)E * 64;
    int scatter_blocks = (int)((scatter_threads + B - 1) / B);
    k_scatter<<<scatter_blocks, B, 0, stream>>>(row, col, x, deg, out, E);
}

// Round 2
// 256.863 us; speedup vs baseline: 1.1442x; 1.1442x over previous
//
#include <hip/hip_runtime.h>

#define D_FEAT 64
#define SCAN_CHUNK 1024
#define SCAN_T 256

// ---------------- fast path: CSR build + gather ----------------

// deg[i] = 1.0 (self loop), counts[i] = 0
__global__ void k_init(float* __restrict__ deg, unsigned* __restrict__ counts, int n) {
    int i = blockIdx.x * blockDim.x + threadIdx.x;
    if (i < n) { deg[i] = 1.0f; counts[i] = 0u; }
}

// deg[col[e]] += 1 (degree over col), counts[row[e]] += 1 (CSR histogram over row)
__global__ void k_count(const int* __restrict__ row, const int* __restrict__ col,
                        float* __restrict__ deg, unsigned* __restrict__ counts, int E) {
    int e = blockIdx.x * blockDim.x + threadIdx.x;
    if (e < E) {
        atomicAdd(&deg[col[e]], 1.0f);
        atomicAdd(&counts[row[e]], 1u);
    }
}

// deg -> rsqrt(deg) in place (deg >= 1 always)
__global__ void k_deg_to_dis(float* __restrict__ deg, int n) {
    int i = blockIdx.x * blockDim.x + threadIdx.x;
    if (i < n) deg[i] = rsqrtf(deg[i]);
}

// Phase A: per-1024-chunk exclusive scan of counts -> offsets, chunk totals -> blockSums
__global__ void k_scan_a(const unsigned* __restrict__ counts, unsigned* __restrict__ offsets,
                         unsigned* __restrict__ blockSums, int n) {
    __shared__ unsigned lds[SCAN_T];
    int b = blockIdx.x, t = threadIdx.x;
    int base = b * SCAN_CHUNK + t * 4;
    unsigned v0 = (base + 0 < n) ? counts[base + 0] : 0u;
    unsigned v1 = (base + 1 < n) ? counts[base + 1] : 0u;
    unsigned v2 = (base + 2 < n) ? counts[base + 2] : 0u;
    unsigned v3 = (base + 3 < n) ? counts[base + 3] : 0u;
    unsigned s = v0 + v1 + v2 + v3;
    lds[t] = s;
    __syncthreads();
    for (int d = 1; d < SCAN_T; d <<= 1) {
        unsigned add = (t >= d) ? lds[t - d] : 0u;
        __syncthreads();
        lds[t] += add;
        __syncthreads();
    }
    unsigned excl = lds[t] - s;
    if (t == SCAN_T - 1) blockSums[b] = lds[t];
    if (base + 0 < n) offsets[base + 0] = excl;
    if (base + 1 < n) offsets[base + 1] = excl + v0;
    if (base + 2 < n) offsets[base + 2] = excl + v0 + v1;
    if (base + 3 < n) offsets[base + 3] = excl + v0 + v1 + v2;
}

// Phase B: single block scans the (<=256) chunk totals -> blockOffs (exclusive)
__global__ void k_scan_b(const unsigned* __restrict__ blockSums, unsigned* __restrict__ blockOffs,
                         int nB) {
    __shared__ unsigned lds[SCAN_T];
    int t = threadIdx.x;
    unsigned v = (t < nB) ? blockSums[t] : 0u;
    lds[t] = v;
    __syncthreads();
    for (int d = 1; d < SCAN_T; d <<= 1) {
        unsigned add = (t >= d) ? lds[t - d] : 0u;
        __syncthreads();
        lds[t] += add;
        __syncthreads();
    }
    if (t < nB) blockOffs[t] = lds[t] - v;
}

// Phase C: offsets[i] += blockOffs[chunk]; cursor[i] = offsets[i]; offsets[n] = E
__global__ void k_scan_c(unsigned* __restrict__ offsets, const unsigned* __restrict__ blockOffs,
                         unsigned* __restrict__ cursor, int n, int E) {
    int i = blockIdx.x * blockDim.x + threadIdx.x;
    if (i < n) {
        unsigned o = offsets[i] + blockOffs[i >> 10];
        offsets[i] = o;
        cursor[i] = o;
    } else if (i == n) {
        offsets[n] = (unsigned)E;
    }
}

// buckets[cursor[row[e]]++] = col[e]
__global__ void k_bucket(const int* __restrict__ row, const int* __restrict__ col,
                         unsigned* __restrict__ cursor, int* __restrict__ buckets, int E) {
    int e = blockIdx.x * blockDim.x + threadIdx.x;
    if (e < E) {
        unsigned pos = atomicAdd(&cursor[row[e]], 1u);
        buckets[pos] = col[e];
    }
}

// one wave per destination node; lane = feature. No atomics, single write of out.
__global__ void k_gather(const float* __restrict__ x, const float* __restrict__ dis,
                         const unsigned* __restrict__ offsets, const int* __restrict__ buckets,
                         float* __restrict__ out, int n) {
    int wave = (blockIdx.x * blockDim.x + threadIdx.x) >> 6;
    int lane = threadIdx.x & 63;
    if (wave >= n) return;
    int r = wave;
    float dr = dis[r];
    unsigned s = offsets[r], e_ = offsets[r + 1];
    // self-loop term: dis[r]^2 * x[r]
    float acc = dr * dr * x[r * D_FEAT + lane];
    unsigned j = s;
    for (; j + 1 < e_; j += 2) {  // pairwise to overlap the two gather loads
        int c0 = buckets[j];
        int c1 = buckets[j + 1];
        float n0 = dr * dis[c0];
        float n1 = dr * dis[c1];
        float x0 = x[c0 * D_FEAT + lane];
        float x1 = x[c1 * D_FEAT + lane];
        acc = fmaf(n0, x0, acc);
        acc = fmaf(n1, x1, acc);
    }
    if (j < e_) {
        int c = buckets[j];
        acc = fmaf(dr * dis[c], x[c * D_FEAT + lane], acc);
    }
    out[r * D_FEAT + lane] = acc;
}

// ---------------- fallback path (round-1 atomic scatter) ----------------

__global__ void k_init_deg(float* __restrict__ deg, int n) {
    int i = blockIdx.x * blockDim.x + threadIdx.x;
    if (i < n) deg[i] = 1.0f;
}
__global__ void k_count_deg(const int* __restrict__ col, float* __restrict__ deg, int E) {
    int e = blockIdx.x * blockDim.x + threadIdx.x;
    if (e < E) atomicAdd(&deg[col[e]], 1.0f);
}
__global__ void k_self_init(const float* __restrict__ x, const float* __restrict__ dis,
                            float* __restrict__ out, int total) {
    int idx = blockIdx.x * blockDim.x + threadIdx.x;
    if (idx < total) {
        int node = idx >> 6;
        float s = dis[node];
        out[idx] = s * s * x[idx];
    }
}
__global__ void k_scatter(const int* __restrict__ row, const int* __restrict__ col,
                          const float* __restrict__ x, const float* __restrict__ dis,
                          float* __restrict__ out, int E) {
    int gtid = blockIdx.x * blockDim.x + threadIdx.x;
    int edge = gtid >> 6;
    int lane = threadIdx.x & 63;
    if (edge < E) {
        int r = row[edge];
        int c = col[edge];
        float nrm = dis[r] * dis[c];
        atomicAdd(&out[r * D_FEAT + lane], nrm * x[c * D_FEAT + lane]);
    }
}

extern "C" void kernel_launch(void* const* d_in, const int* in_sizes, int n_in,
                              void* d_out, int out_size, void* d_ws, size_t ws_size,
                              hipStream_t stream) {
    const float* x = (const float*)d_in[0];
    const int* ei = (const int*)d_in[1];

    const int N = in_sizes[0] / D_FEAT;   // 100000
    const int E = in_sizes[1] / 2;        // 1000000
    const int* row = ei;
    const int* col = ei + E;

    float* out = (float*)d_out;
    const int B = 256;

    // ws layout (all 4B words): deg[N] | offsets[N+1] | cursor[N] | blockSums[256] | blockOffs[256] | buckets[E]
    size_t need = ((size_t)3 * N + 1 + 512 + (size_t)E) * 4;
    int nB = (N + SCAN_CHUNK - 1) / SCAN_CHUNK;

    if (ws_size >= need && nB <= SCAN_T) {
        float*    deg       = (float*)d_ws;
        unsigned* offsets   = (unsigned*)(deg + N);
        unsigned* cursor    = offsets + (N + 1);
        unsigned* blockSums = cursor + N;
        unsigned* blockOffs = blockSums + 256;
        int*      buckets   = (int*)(blockOffs + 256);
        unsigned* counts    = cursor;  // counts reuses cursor storage (overwritten by scan_c)

        k_init<<<(N + B - 1) / B, B, 0, stream>>>(deg, counts, N);
        k_count<<<(E + B - 1) / B, B, 0, stream>>>(row, col, deg, counts, E);
        k_deg_to_dis<<<(N + B - 1) / B, B, 0, stream>>>(deg, N);
        k_scan_a<<<nB, SCAN_T, 0, stream>>>(counts, offsets, blockSums, N);
        k_scan_b<<<1, SCAN_T, 0, stream>>>(blockSums, blockOffs, nB);
        k_scan_c<<<(N + 1 + B - 1) / B, B, 0, stream>>>(offsets, blockOffs, cursor, N, E);
        k_bucket<<<(E + B - 1) / B, B, 0, stream>>>(row, col, cursor, buckets, E);
        long long gthreads = (long long)N * 64;
        k_gather<<<(int)((gthreads + B - 1) / B), B, 0, stream>>>(x, deg, offsets, buckets, out, N);
    } else {
        // fallback: atomic scatter (needs only N floats of ws)
        float* deg = (float*)d_ws;
        k_init_deg<<<(N + B - 1) / B, B, 0, stream>>>(deg, N);
        k_count_deg<<<(E + B - 1) / B, B, 0, stream>>>(col, deg, E);
        k_deg_to_dis<<<(N + B - 1) / B, B, 0, stream>>>(deg, N);
        int total = N * D_FEAT;
        k_self_init<<<(total + B - 1) / B, B, 0, stream>>>(x, deg, out, total);
        long long st = (long long)E * 64;
        k_scatter<<<(int)((st + B - 1) / B), B, 0, stream>>>(row, col, x, deg, out, E);
    }
}